// Round 7
// baseline (149.389 us; speedup 1.0000x reference)
//
#include <hip/hip_runtime.h>

// LambdaLoss: B=4096 lists, L=128 items.
// per list: sum over pairs rel_i > rel_j of |rd| * softplus(-(p_i - p_j)),
// divided by valid-pair count; output = mean over lists with >=1 valid pair.
//
// Decomposition: with E_k = exp2(p_k*log2e), y_k = p_k*log2e:
//   softplus(-(p_w - p_l)) = ln2 * (log2(E_i + E_j) - y_w)
//   sum_pairs |rd|*y_w = sum_i y_i * W_i,  W_i = sum_v c_v * relu(r_i - v)
// so the per-pair loop needs only E_j and r_j. R7: pack r (3 bits) into E's
// low mantissa bits -> ONE ds_read_b32 per pair (rel err 2^-20, harmless).
// Per-pair VALU: and, sub_i32, cvt, add_f32, v_log, fma(|.| modifier).
//
// Kernel 1: one block per list, triangular pairs via circular offsets
// (i, i+d), d=1..64 (d=64 masked to i<64), mirrored LDS (no wrap mask).
// Finalize fused via last-block-done: per-list results published with
// device-scope (sc0/sc1) atomic stores -> no stale-L2 hazard across XCDs
// (per-XCD L2s are non-coherent; the 0xAA poison fill may sit in any L2);
// single ACQ_REL ticket; 4096th block reduces and writes out[0].

#define LB 4096
#define LLEN 128
#define MIR 192   // mirrored length: max index 129 + 62 = 191

#define EXP2F(x) __builtin_amdgcn_exp2f(x)   // v_exp_f32 (2^x)
#define LOG2F(x) __builtin_amdgcn_logf(x)    // v_log_f32 (log2)

union f2u {
  float2 f;
  unsigned long long u;
};

__global__ __launch_bounds__(256) void lambda_pairs_kernel(
    const float* __restrict__ pred, const float* __restrict__ rel,
    unsigned long long* __restrict__ per2u, unsigned int* __restrict__ ticket,
    float* __restrict__ out) {
  __shared__ unsigned int su[MIR];   // packed (E | r), mirrored
  __shared__ int hist[8];
  __shared__ float wsum[4];
  __shared__ int lastFlag;

  const int t = threadIdx.x;
  const int b = blockIdx.x;
  const int i = t & (LLEN - 1);

  constexpr float LOG2E = 1.4426950408889634f;
  constexpr float LN2   = 0.6931471805599453f;

  // stage: every thread computes its row's packed (E,r); t in [128,192) mirrors
  const float pi  = pred[b * LLEN + i];
  const float ri  = rel[b * LLEN + i];
  const int   rii = (int)ri;
  const float yi  = pi * LOG2E;
  const float Ei  = EXP2F(yi);
  const unsigned int pk = (__float_as_uint(Ei) & ~7u) | (unsigned int)rii;
  if (t < 8) hist[t] = 0;
  if (t < MIR) su[t] = pk;
  __syncthreads();
  if (t < LLEN) atomicAdd(&hist[rii], 1);
  __syncthreads();   // hist and su both ready

  // thread half selects odd (d=1,3,..,63) or even (d=2,4,..,64) offsets
  const int j0 = i + 1 + (t >> 7);   // max addr: 129 + 62 = 191
  float acc = 0.f;

#pragma unroll 8
  for (int k = 0; k < 31; ++k) {
    unsigned int v = su[j0 + 2 * k];
    float rdf = (float)(rii - (int)(v & 7u));     // rel diff
    float lg  = LOG2F(Ei + __uint_as_float(v));   // log2(Ei+Ej), Ej perturbed 2^-20
    acc = fmaf(fabsf(rdf), lg, acc);              // |rd|=0 for ties -> no-op
  }
  { // tail: d=63 (lower half, all i) or d=64 (upper half, only i<64)
    unsigned int v = su[j0 + 62];
    float rdf = (float)(rii - (int)(v & 7u));
    float w   = ((t < 128) || (i < 64)) ? fabsf(rdf) : 0.f;
    acc = fmaf(w, LOG2F(Ei + __uint_as_float(v)), acc);
  }

  // per-row winner-y correction: acc -= y_i * W_i (one thread per row)
  if (t < LLEN) {
    float W = 0.f;
#pragma unroll
    for (int v = 0; v < 5; ++v)
      W = fmaf((float)hist[v], fmaxf(ri - (float)v, 0.f), W);
    acc = fmaf(-yi, W, acc);
  }

  // wave (64-lane) shuffle reduction, then cross-wave via LDS
  for (int off = 32; off > 0; off >>= 1) acc += __shfl_down(acc, off, 64);
  if ((t & 63) == 0) wsum[t >> 6] = acc;
  __syncthreads();

  if (t == 0) {
    float ssum = (wsum[0] + wsum[1]) + (wsum[2] + wsum[3]);
    int same = 0;
#pragma unroll
    for (int v = 0; v < 5; ++v) same += hist[v] * (hist[v] - 1) / 2;
    const int cnt = (LLEN * (LLEN - 1) / 2) - same;
    f2u r;
    r.f = make_float2((cnt > 0) ? (LN2 * ssum) / (float)cnt : 0.f,
                      (cnt > 0) ? 1.f : 0.f);
    // device-scope store: bypasses non-coherent per-XCD L2s
    __hip_atomic_store(&per2u[b], r.u, __ATOMIC_RELAXED, __HIP_MEMORY_SCOPE_AGENT);
    unsigned int old = __hip_atomic_fetch_add(ticket, 1u, __ATOMIC_ACQ_REL,
                                              __HIP_MEMORY_SCOPE_AGENT);
    lastFlag = (old == LB - 1) ? 1 : 0;
  }
  __syncthreads();

  if (lastFlag) {
    // final reduction: device-scope loads (fresh data, no L2 staleness)
    float s = 0.f, n = 0.f;
    for (int idx = t; idx < LB; idx += 256) {
      f2u v;
      v.u = __hip_atomic_load(&per2u[idx], __ATOMIC_RELAXED,
                              __HIP_MEMORY_SCOPE_AGENT);
      s += v.f.x;
      n += v.f.y;
    }
    for (int off = 32; off > 0; off >>= 1) {
      s += __shfl_down(s, off, 64);
      n += __shfl_down(n, off, 64);
    }
    if ((t & 63) == 0) { wsum[t >> 6] = s; }
    __syncthreads();
    __shared__ float wcnt[4];
    if ((t & 63) == 0) { wcnt[t >> 6] = n; }
    __syncthreads();
    if (t == 0) {
      float ts = (wsum[0] + wsum[1]) + (wsum[2] + wsum[3]);
      float tn = (wcnt[0] + wcnt[1]) + (wcnt[2] + wcnt[3]);
      out[0] = (tn > 0.f) ? ts / tn : 0.f;
    }
  }
}

extern "C" void kernel_launch(void* const* d_in, const int* in_sizes, int n_in,
                              void* d_out, int out_size, void* d_ws, size_t ws_size,
                              hipStream_t stream) {
  const float* pred = (const float*)d_in[0];
  const float* rel  = (const float*)d_in[1];
  float* out = (float*)d_out;

  unsigned long long* per2u = (unsigned long long*)d_ws;       // [4096]
  unsigned int* ticket = (unsigned int*)(per2u + LB);          // [1]

  hipMemsetAsync(ticket, 0, sizeof(unsigned int), stream);
  lambda_pairs_kernel<<<dim3(LB), dim3(256), 0, stream>>>(pred, rel, per2u,
                                                          ticket, out);
}

// Round 8
// 66.034 us; speedup vs baseline: 2.2623x; 2.2623x over previous
//
#include <hip/hip_runtime.h>

// LambdaLoss: B=4096 lists, L=128 items.
// per list: sum over pairs rel_i > rel_j of |rd| * softplus(-(p_i - p_j)),
// divided by valid-pair count; output = mean over lists with >=1 valid pair.
//
// Decomposition: with E_k = exp2(p_k*log2e), y_k = p_k*log2e:
//   softplus(-(p_w - p_l)) = ln2 * (log2(E_i + E_j) - y_w)
//   sum_pairs |rd|*y_w = sum_i y_i * W_i,  W_i = sum_v c_v * relu(r_i - v)
// so the per-pair loop needs only E_j and r_j, PACKED into one dword
// (r in E's 3 low mantissa bits, rel err 2^-20) -> ONE ds_read_b32/pair.
//
// Kernel 1: one block per list, triangular pairs via circular offsets
// (i, i+d), d=1..64 (d=64 masked to i<64), mirrored LDS (no wrap mask).
// Histogram via wave ballots (no LDS atomics, single barrier).
// Per-list float2 store to ws. NO global atomics / tickets:
//   R4: 8192 same-address float atomicAdds -> +100us serialized drain.
//   R7: 4096 ACQ_REL ticket RMWs (release fence per block) -> +97us.
// Kernel 2: single block, coalesced float4 reduction of 4096 float2.

#define LB 4096
#define LLEN 128
#define MIR 192   // mirrored length: max index 129 + 62 = 191

#define EXP2F(x) __builtin_amdgcn_exp2f(x)   // v_exp_f32 (2^x)
#define LOG2F(x) __builtin_amdgcn_logf(x)    // v_log_f32 (log2)

__global__ __launch_bounds__(256) void lambda_pairs_kernel(
    const float* __restrict__ pred, const float* __restrict__ rel,
    float2* __restrict__ per2) {
  __shared__ unsigned int su[MIR];   // packed (E | r), mirrored
  __shared__ int whist[2][5];        // per-wave (rows 0..63 / 64..127) rel counts
  __shared__ float wsum[4];

  const int t = threadIdx.x;
  const int b = blockIdx.x;
  const int i = t & (LLEN - 1);

  constexpr float LOG2E = 1.4426950408889634f;
  constexpr float LN2   = 0.6931471805599453f;

  // stage: every thread computes its row's packed (E,r); t in [128,192) mirrors
  const float pi  = pred[b * LLEN + i];
  const float ri  = rel[b * LLEN + i];
  const int   rii = (int)ri;
  const float yi  = pi * LOG2E;
  const float Ei  = EXP2F(yi);
  if (t < MIR) su[t] = (__float_as_uint(Ei) & ~7u) | (unsigned int)rii;

  // 5-bin histogram via ballots on waves 0,1 (rows 0..127), no atomics
  if (t < LLEN) {
#pragma unroll
    for (int v = 0; v < 5; ++v) {
      unsigned long long m = __ballot(rii == v);
      if ((t & 63) == 0) whist[t >> 6][v] = (int)__popcll(m);
    }
  }
  __syncthreads();

  // thread half selects odd (d=1,3,..,63) or even (d=2,4,..,64) offsets
  const int j0 = i + 1 + (t >> 7);   // max addr: 129 + 62 = 191
  float acc = 0.f;

#pragma unroll 8
  for (int k = 0; k < 31; ++k) {
    unsigned int v = su[j0 + 2 * k];
    float rdf = (float)(rii - (int)(v & 7u));     // rel diff
    float lg  = LOG2F(Ei + __uint_as_float(v));   // log2(Ei+Ej), Ej perturbed 2^-20
    acc = fmaf(fabsf(rdf), lg, acc);              // |rd|=0 for ties -> no-op
  }
  { // tail: d=63 (lower half, all i) or d=64 (upper half, only i<64)
    unsigned int v = su[j0 + 62];
    float rdf = (float)(rii - (int)(v & 7u));
    float w   = ((t < 128) || (i < 64)) ? fabsf(rdf) : 0.f;
    acc = fmaf(w, LOG2F(Ei + __uint_as_float(v)), acc);
  }

  // per-row winner-y correction: acc -= y_i * W_i (one thread per row)
  if (t < LLEN) {
    float W = 0.f;
#pragma unroll
    for (int v = 0; v < 5; ++v) {
      int cv = whist[0][v] + whist[1][v];          // LDS broadcast reads
      W = fmaf((float)cv, fmaxf(ri - (float)v, 0.f), W);
    }
    acc = fmaf(-yi, W, acc);
  }

  // wave (64-lane) shuffle reduction, then cross-wave via LDS
  for (int off = 32; off > 0; off >>= 1) acc += __shfl_down(acc, off, 64);
  if ((t & 63) == 0) wsum[t >> 6] = acc;
  __syncthreads();
  if (t == 0) {
    float ssum = (wsum[0] + wsum[1]) + (wsum[2] + wsum[3]);
    int same = 0;
#pragma unroll
    for (int v = 0; v < 5; ++v) {
      int cv = whist[0][v] + whist[1][v];
      same += cv * (cv - 1) / 2;
    }
    const int cnt = (LLEN * (LLEN - 1) / 2) - same;
    per2[b] = make_float2((cnt > 0) ? (LN2 * ssum) / (float)cnt : 0.f,
                          (cnt > 0) ? 1.f : 0.f);
  }
}

__global__ __launch_bounds__(256) void lambda_finalize_kernel(
    const float2* __restrict__ per2, float* __restrict__ out) {
  __shared__ float wsum[4], wcnt[4];
  const int t = threadIdx.x;
  const float4* v = (const float4*)per2;   // 4096 float2 = 2048 float4
  float s = 0.f, n = 0.f;
#pragma unroll
  for (int idx = t; idx < 2048; idx += 256) {
    float4 q = v[idx];
    s += q.x + q.z;
    n += q.y + q.w;
  }
  for (int off = 32; off > 0; off >>= 1) {
    s += __shfl_down(s, off, 64);
    n += __shfl_down(n, off, 64);
  }
  if ((t & 63) == 0) { wsum[t >> 6] = s; wcnt[t >> 6] = n; }
  __syncthreads();
  if (t == 0) {
    float ts = (wsum[0] + wsum[1]) + (wsum[2] + wsum[3]);
    float tn = (wcnt[0] + wcnt[1]) + (wcnt[2] + wcnt[3]);
    out[0] = (tn > 0.f) ? ts / tn : 0.f;
  }
}

extern "C" void kernel_launch(void* const* d_in, const int* in_sizes, int n_in,
                              void* d_out, int out_size, void* d_ws, size_t ws_size,
                              hipStream_t stream) {
  const float* pred = (const float*)d_in[0];
  const float* rel  = (const float*)d_in[1];
  float* out   = (float*)d_out;
  float2* per2 = (float2*)d_ws;   // [4096] (ratio, valid)

  lambda_pairs_kernel<<<dim3(LB), dim3(256), 0, stream>>>(pred, rel, per2);
  lambda_finalize_kernel<<<dim3(1), dim3(256), 0, stream>>>(per2, out);
}